// Round 7
// baseline (106.263 us; speedup 1.0000x reference)
//
#include <hip/hip_runtime.h>
#include <math.h>

#define NN 4096
#define MM 8
#define BLOCK 256
#define JT 64
#define CCHUNK 32
#define FOUR_PI_F 12.566370614359172f
#define EPS_F 1e-8f
#define LOG2E_F 1.4426950408889634f

// out[i][m] = sum_j exp(-d_ij/lam_m)/(4*pi*D_m*d_ij) * secretion[j][m]*active[j]
// d_ij = max(sqrt(|p_i-p_j|^2+eps), r_j)
//
// Structure: single fused kernel, grid (NN/BLOCK, CCHUNK). Block owns 256 i's
// and a 128-wide j-range (2 LDS tiles of 64, active-compacted); accumulates
// into d_out via hardware f32 atomics (out is zeroed by a memset in-stream).
//
// Math notes:
//  * squared-domain clamp: max(sqrt(d2+eps), r) == sqrt(max(d2+eps, r^2));
//    1/dist == rsqrt(...) — one v_rsq replaces v_sqrt+v_rcp.
//  * exp(-d/lam) = exp2(d*na), na = -log2(e)/lam.
//  * ACTIVE COMPACTION: inactive j contribute exactly 0 — staging compacts
//    tiles to active j's via ballot+popcount prefix (order-preserving).
//  * lam bit-identical for m in {0,1,5} with the bench constants; wave-uniform
//    runtime check picks a loop sharing one exp2 across those channels.

template <bool DUP015>
__device__ __forceinline__ void run_tile(
    int nact, const float4* __restrict__ sj, const float4* __restrict__ ss,
    float px, float py, float pz, const float* __restrict__ na,
    float* __restrict__ acc)
{
#pragma unroll 4
    for (int jj = 0; jj < nact; ++jj) {
        const float4 pj = sj[jj];
        const float4 s0 = ss[jj * 2 + 0];
        const float4 s1 = ss[jj * 2 + 1];
        float dx = px - pj.x;
        float dy = py - pj.y;
        float dz = pz - pj.z;
        float d2 = fmaf(dx, dx, fmaf(dy, dy, fmaf(dz, dz, EPS_F)));
        float d2c = fmaxf(d2, pj.w);            // clamp in squared domain
        float rs = __builtin_amdgcn_rsqf(d2c);  // = 1/dist_clamped
        float dcl = d2c * rs;                   // = dist_clamped

        float ers[MM];
        if constexpr (DUP015) {
            float eA = __builtin_amdgcn_exp2f(dcl * na[0]) * rs;
            ers[0] = eA; ers[1] = eA; ers[5] = eA;
            ers[2] = __builtin_amdgcn_exp2f(dcl * na[2]) * rs;
            ers[3] = __builtin_amdgcn_exp2f(dcl * na[3]) * rs;
            ers[4] = __builtin_amdgcn_exp2f(dcl * na[4]) * rs;
            ers[6] = __builtin_amdgcn_exp2f(dcl * na[6]) * rs;
            ers[7] = __builtin_amdgcn_exp2f(dcl * na[7]) * rs;
        } else {
#pragma unroll
            for (int m = 0; m < MM; ++m)
                ers[m] = __builtin_amdgcn_exp2f(dcl * na[m]) * rs;
        }

        const float s[MM] = {s0.x, s0.y, s0.z, s0.w, s1.x, s1.y, s1.z, s1.w};
#pragma unroll
        for (int m = 0; m < MM; ++m)
            acc[m] = fmaf(ers[m], s[m], acc[m]);
    }
}

__global__ __launch_bounds__(BLOCK) void diff_fused(
    const float* __restrict__ pos,        // NN x 3
    const float* __restrict__ radius,     // NN
    const float* __restrict__ secretion,  // NN x MM
    const float* __restrict__ Dc,         // MM
    const float* __restrict__ Kd,         // MM
    const int*   __restrict__ active,     // NN (0/1)
    float* out,                           // NN x MM, pre-zeroed
    int jrange)
{
    __shared__ float4 sj[JT];       // {x,y,z,r^2} of k-th ACTIVE j
    __shared__ float4 ss[JT * 2];   // premult secretion/(4*pi*D_m), 2 halves
    __shared__ int s_nact;

    const int tid = threadIdx.x;
    const int i = blockIdx.x * BLOCK + tid;
    const int j0base = blockIdx.y * jrange;

    float na[MM], invD[MM], acc[MM];
#pragma unroll
    for (int m = 0; m < MM; ++m) {
        float lam = sqrtf(Dc[m] / Kd[m]);
        na[m] = -LOG2E_F / lam;
        invD[m] = 1.0f / (FOUR_PI_F * Dc[m]);
        acc[m] = 0.0f;
    }
    const bool dup015 = (na[0] == na[1]) && (na[0] == na[5]);

    const float px = pos[i * 3 + 0];
    const float py = pos[i * 3 + 1];
    const float pz = pos[i * 3 + 2];

    for (int t = 0; t < jrange; t += JT) {
        const int j0 = j0base + t;
        __syncthreads();  // protect LDS from previous tile's readers

        // Wave 0 stages + compacts: lane tid owns j0+tid. (Condition is
        // wave-uniform: tid<64 is exactly wave 0, so ballot is well-defined.)
        if (tid < JT) {
            const int j = j0 + tid;
            const bool act = (active[j] != 0);
            const unsigned long long mask = __ballot(act);
            if (tid == 0) s_nact = __popcll(mask);
            if (act) {
                const int k = __popcll(mask & ((1ull << tid) - 1ull));
                const float r = radius[j];
                sj[k] = make_float4(pos[j * 3 + 0], pos[j * 3 + 1],
                                    pos[j * 3 + 2], r * r);
                const float4 s0 =
                    reinterpret_cast<const float4*>(secretion)[j * 2 + 0];
                const float4 s1 =
                    reinterpret_cast<const float4*>(secretion)[j * 2 + 1];
                ss[k * 2 + 0] = make_float4(s0.x * invD[0], s0.y * invD[1],
                                            s0.z * invD[2], s0.w * invD[3]);
                ss[k * 2 + 1] = make_float4(s1.x * invD[4], s1.y * invD[5],
                                            s1.z * invD[6], s1.w * invD[7]);
            }
        }
        __syncthreads();

        const int nact = s_nact;
        if (dup015)
            run_tile<true>(nact, sj, ss, px, py, pz, na, acc);
        else
            run_tile<false>(nact, sj, ss, px, py, pz, na, acc);
    }

    // Accumulate into out via hardware f32 atomics (device scope).
    float* dst = out + (size_t)i * MM;
#pragma unroll
    for (int m = 0; m < MM; ++m)
        unsafeAtomicAdd(dst + m, acc[m]);
}

extern "C" void kernel_launch(void* const* d_in, const int* in_sizes, int n_in,
                              void* d_out, int out_size, void* d_ws, size_t ws_size,
                              hipStream_t stream) {
    const float* pos       = (const float*)d_in[0];
    const float* radius    = (const float*)d_in[1];
    const float* secretion = (const float*)d_in[2];
    const float* Dc        = (const float*)d_in[3];
    const float* Kd        = (const float*)d_in[4];
    const int*   active    = (const int*)d_in[5];
    float* out = (float*)d_out;

    // Zero the (0xAA-poisoned) output; atomic accumulation follows.
    hipMemsetAsync(out, 0, (size_t)NN * MM * sizeof(float), stream);

    dim3 grid(NN / BLOCK, CCHUNK);
    diff_fused<<<grid, BLOCK, 0, stream>>>(pos, radius, secretion, Dc, Kd,
                                           active, out, NN / CCHUNK);
}

// Round 9
// 90.768 us; speedup vs baseline: 1.1707x; 1.1707x over previous
//
#include <hip/hip_runtime.h>
#include <math.h>

#define NN 4096
#define MM 8
#define BLOCK 256
#define IPT 2                  // i-rows per thread
#define IBLK (BLOCK * IPT)     // 512 i-rows per block
#define CC 128                 // j-chunks (grid.y)
#define JT 32                  // j-tile size = NN/CC
#define FOUR_PI_F 12.566370614359172f
#define EPS_F 1e-8f
#define LOG2E_F 1.4426950408889634f

// out[i][m] = sum_j exp(-d_ij/lam_m)/(4*pi*D_m*d_ij) * secretion[j][m]*active[j]
// d_ij = max(sqrt(|p_i-p_j|^2+eps), r_j)
//
// R8 structure: partial+reduce (R7's atomics caused 32MB of cross-XCD HBM
// writeback; reverted). grid (8,128)=1024 blocks, 4 waves/SIMD; IPT=2 gives
// 2 independent compute chains per thread sharing each LDS broadcast.
//
// Math: squared-domain clamp (rsqrt replaces sqrt+rcp); exp2(d*na) with
// na=-log2e/lam; active-compaction via ballot prefix; runtime-gated
// specializations: VAR1 shares one exp2 across bit-equal lam (m 0,1,5);
// VAR2 additionally exploits lam ratios 20:10:5 (e3=e2^2, e4=e3^2):
// 4 exp2 + 1 rsq per pair. Generic VAR0 for arbitrary inputs.

template <int VAR>
__device__ __forceinline__ void run_tile(
    int nact, const float4* __restrict__ sj, const float4* __restrict__ ss,
    const float* __restrict__ px, const float* __restrict__ py,
    const float* __restrict__ pz, const float* __restrict__ na,
    float acc[IPT][MM])
{
#pragma unroll 2
    for (int jj = 0; jj < nact; ++jj) {
        const float4 pj = sj[jj];
        const float4 s0 = ss[jj * 2 + 0];
        const float4 s1 = ss[jj * 2 + 1];
#pragma unroll
        for (int r = 0; r < IPT; ++r) {
            float dx = px[r] - pj.x;
            float dy = py[r] - pj.y;
            float dz = pz[r] - pj.z;
            float d2 = fmaf(dx, dx, fmaf(dy, dy, fmaf(dz, dz, EPS_F)));
            float d2c = fmaxf(d2, pj.w);            // clamp in squared domain
            float rs = __builtin_amdgcn_rsqf(d2c);  // 1/dist
            float dcl = d2c * rs;                   // dist

            float f[MM];  // e_m * rs
            if constexpr (VAR == 2) {
                float eA = __builtin_amdgcn_exp2f(dcl * na[0]);  // m0,1,5
                float e2 = __builtin_amdgcn_exp2f(dcl * na[2]);
                float e3 = e2 * e2;   // lam3 = lam2/2
                float e4 = e3 * e3;   // lam4 = lam3/2
                float e6 = __builtin_amdgcn_exp2f(dcl * na[6]);
                float e7 = __builtin_amdgcn_exp2f(dcl * na[7]);
                float fA = eA * rs;
                f[0] = fA; f[1] = fA; f[5] = fA;
                f[2] = e2 * rs; f[3] = e3 * rs; f[4] = e4 * rs;
                f[6] = e6 * rs; f[7] = e7 * rs;
            } else if constexpr (VAR == 1) {
                float fA = __builtin_amdgcn_exp2f(dcl * na[0]) * rs;
                f[0] = fA; f[1] = fA; f[5] = fA;
                f[2] = __builtin_amdgcn_exp2f(dcl * na[2]) * rs;
                f[3] = __builtin_amdgcn_exp2f(dcl * na[3]) * rs;
                f[4] = __builtin_amdgcn_exp2f(dcl * na[4]) * rs;
                f[6] = __builtin_amdgcn_exp2f(dcl * na[6]) * rs;
                f[7] = __builtin_amdgcn_exp2f(dcl * na[7]) * rs;
            } else {
#pragma unroll
                for (int m = 0; m < MM; ++m)
                    f[m] = __builtin_amdgcn_exp2f(dcl * na[m]) * rs;
            }

            const float s[MM] = {s0.x, s0.y, s0.z, s0.w,
                                 s1.x, s1.y, s1.z, s1.w};
#pragma unroll
            for (int m = 0; m < MM; ++m)
                acc[r][m] = fmaf(f[m], s[m], acc[r][m]);
        }
    }
}

// grid = (NN/IBLK, C). Block: 512 i-rows x one 32-wide j-tile (compacted).
__global__ __launch_bounds__(BLOCK) void diff_partial(
    const float* __restrict__ pos, const float* __restrict__ radius,
    const float* __restrict__ secretion, const float* __restrict__ Dc,
    const float* __restrict__ Kd, const int* __restrict__ active,
    float* __restrict__ partial,   // C x NN x MM
    int ntiles)                    // tiles per block (1 when C=128)
{
    __shared__ float4 sj[JT];      // {x,y,z,r^2} of k-th ACTIVE j
    __shared__ float4 ss[JT * 2];  // premult secretion/(4*pi*D_m)
    __shared__ int s_nact;

    const int tid = threadIdx.x;
    const int i0 = blockIdx.x * IBLK + tid;       // row for r=0
    const int i1 = i0 + BLOCK;                    // row for r=1
    const int j0base = blockIdx.y * (JT * ntiles);

    float na[MM], invD[MM];
    float acc[IPT][MM];
#pragma unroll
    for (int m = 0; m < MM; ++m) {
        float lam = sqrtf(Dc[m] / Kd[m]);
        na[m] = -LOG2E_F / lam;
        invD[m] = 1.0f / (FOUR_PI_F * Dc[m]);
        acc[0][m] = 0.0f; acc[1][m] = 0.0f;
    }
    const bool dup015 = (na[0] == na[1]) && (na[0] == na[5]);
    const bool chain =
        dup015 &&
        (fabsf(na[3] - 2.0f * na[2]) <= 4e-6f * fabsf(na[3])) &&
        (fabsf(na[4] - 2.0f * na[3]) <= 4e-6f * fabsf(na[4]));

    const float px[IPT] = {pos[i0 * 3 + 0], pos[i1 * 3 + 0]};
    const float py[IPT] = {pos[i0 * 3 + 1], pos[i1 * 3 + 1]};
    const float pz[IPT] = {pos[i0 * 3 + 2], pos[i1 * 3 + 2]};

    for (int t = 0; t < ntiles; ++t) {
        const int j0 = j0base + t * JT;
        __syncthreads();  // protect LDS from previous tile's readers

        // Wave 0, lanes 0..31 stage + compact (lanes >=32 idle in ballot -> 0 bits).
        if (tid < JT) {
            const int j = j0 + tid;
            const bool act = (active[j] != 0);
            const unsigned long long mask = __ballot(act);
            if (tid == 0) s_nact = __popcll(mask);
            if (act) {
                const int k = __popcll(mask & ((1ull << tid) - 1ull));
                const float r = radius[j];
                sj[k] = make_float4(pos[j * 3 + 0], pos[j * 3 + 1],
                                    pos[j * 3 + 2], r * r);
                const float4 s0 =
                    reinterpret_cast<const float4*>(secretion)[j * 2 + 0];
                const float4 s1 =
                    reinterpret_cast<const float4*>(secretion)[j * 2 + 1];
                ss[k * 2 + 0] = make_float4(s0.x * invD[0], s0.y * invD[1],
                                            s0.z * invD[2], s0.w * invD[3]);
                ss[k * 2 + 1] = make_float4(s1.x * invD[4], s1.y * invD[5],
                                            s1.z * invD[6], s1.w * invD[7]);
            }
        }
        __syncthreads();

        const int nact = s_nact;
        if (chain)       run_tile<2>(nact, sj, ss, px, py, pz, na, acc);
        else if (dup015) run_tile<1>(nact, sj, ss, px, py, pz, na, acc);
        else             run_tile<0>(nact, sj, ss, px, py, pz, na, acc);
    }

    float* base = partial + (size_t)blockIdx.y * NN * MM;
    float4* d0 = reinterpret_cast<float4*>(base + (size_t)i0 * MM);
    float4* d1 = reinterpret_cast<float4*>(base + (size_t)i1 * MM);
    d0[0] = make_float4(acc[0][0], acc[0][1], acc[0][2], acc[0][3]);
    d0[1] = make_float4(acc[0][4], acc[0][5], acc[0][6], acc[0][7]);
    d1[0] = make_float4(acc[1][0], acc[1][1], acc[1][2], acc[1][3]);
    d1[1] = make_float4(acc[1][4], acc[1][5], acc[1][6], acc[1][7]);
}

// Reduce: 128 blocks x 256 thr. tx=output float4 (64/block), ty=c-slice (4).
__global__ __launch_bounds__(BLOCK) void diff_reduce(
    const float4* __restrict__ partial, float4* __restrict__ out, int C)
{
    __shared__ float4 red[4][64];
    const int tx = threadIdx.x & 63;
    const int ty = threadIdx.x >> 6;
    const int o = blockIdx.x * 64 + tx;  // 0 .. NN*MM/4-1

    float4 s = make_float4(0.f, 0.f, 0.f, 0.f);
    for (int c = ty; c < C; c += 4) {
        const float4 p = partial[(size_t)c * (NN * MM / 4) + o];
        s.x += p.x; s.y += p.y; s.z += p.z; s.w += p.w;
    }
    red[ty][tx] = s;
    __syncthreads();
    if (ty == 0) {
        const float4 a = red[1][tx], b = red[2][tx], c4 = red[3][tx];
        s.x += a.x + b.x + c4.x;
        s.y += a.y + b.y + c4.y;
        s.z += a.z + b.z + c4.z;
        s.w += a.w + b.w + c4.w;
        out[o] = s;
    }
}

extern "C" void kernel_launch(void* const* d_in, const int* in_sizes, int n_in,
                              void* d_out, int out_size, void* d_ws, size_t ws_size,
                              hipStream_t stream) {
    const float* pos       = (const float*)d_in[0];
    const float* radius    = (const float*)d_in[1];
    const float* secretion = (const float*)d_in[2];
    const float* Dc        = (const float*)d_in[3];
    const float* Kd        = (const float*)d_in[4];
    const int*   active    = (const int*)d_in[5];
    float* out = (float*)d_out;

    const size_t slice = (size_t)NN * MM * sizeof(float);  // 128 KB

    int C = CC;
    while (C > 4 && (size_t)C * slice > ws_size) C >>= 1;
    const int ntiles = NN / (C * JT);  // 1 at C=128

    float* partial = (float*)d_ws;
    dim3 grid(NN / IBLK, C);
    diff_partial<<<grid, BLOCK, 0, stream>>>(pos, radius, secretion, Dc, Kd,
                                             active, partial, ntiles);
    diff_reduce<<<NN * MM / 4 / 64, BLOCK, 0, stream>>>(
        (const float4*)partial, (float4*)out, C);
}

// Round 11
// 80.721 us; speedup vs baseline: 1.3164x; 1.1245x over previous
//
#include <hip/hip_runtime.h>
#include <math.h>

#define NN 4096
#define MM 8
#define BLOCK 256
#define CC 64                  // j-chunks (grid.y)
#define JT 64                  // j-tile size
#define FOUR_PI_F 12.566370614359172f
#define EPS_F 1e-8f
#define LOG2E_F 1.4426950408889634f

// out[i][m] = sum_j exp(-d_ij/lam_m)/(4*pi*D_m*d_ij) * secretion[j][m]*active[j]
// d_ij = max(sqrt(|p_i-p_j|^2+eps), r_j)
//
// R10: partial+reduce. Partial: grid (16,64)=1024 blocks (4 waves/SIMD), each
// block = 256 i-rows x one 64-j tile (active-compacted), 8 MB partial buffer
// (half of R9's 16 MB). Reduce: 512 blocks, 16 outputs x 16 c-slices + LDS
// tree (R9's 128-block reduce was latency-bound: ~0.5 waves/SIMD and too few
// loads in flight).
//
// Math: squared-domain clamp (one rsqrt replaces sqrt+rcp); exp2(d*na),
// na=-log2e/lam; active-compaction via ballot prefix (order-preserving);
// runtime-gated specializations: VAR1 shares one exp2 across bit-equal lam
// (m 0,1,5); VAR2 additionally uses lam ratios 20:10:5 (e3=e2^2, e4=e3^2):
// 4 exp2 + 1 rsq per pair. Generic VAR0 for arbitrary inputs.

template <int VAR>
__device__ __forceinline__ void run_tile(
    int nact, const float4* __restrict__ sj, const float4* __restrict__ ss,
    float px, float py, float pz, const float* __restrict__ na,
    float* __restrict__ acc)
{
#pragma unroll 2
    for (int jj = 0; jj < nact; ++jj) {
        const float4 pj = sj[jj];
        const float4 s0 = ss[jj * 2 + 0];
        const float4 s1 = ss[jj * 2 + 1];
        float dx = px - pj.x;
        float dy = py - pj.y;
        float dz = pz - pj.z;
        float d2 = fmaf(dx, dx, fmaf(dy, dy, fmaf(dz, dz, EPS_F)));
        float d2c = fmaxf(d2, pj.w);            // clamp in squared domain
        float rs = __builtin_amdgcn_rsqf(d2c);  // 1/dist
        float dcl = d2c * rs;                   // dist

        float f[MM];  // e_m * rs
        if constexpr (VAR == 2) {
            float eA = __builtin_amdgcn_exp2f(dcl * na[0]);  // m0,1,5
            float e2 = __builtin_amdgcn_exp2f(dcl * na[2]);
            float e3 = e2 * e2;   // lam3 = lam2/2
            float e4 = e3 * e3;   // lam4 = lam3/2
            float e6 = __builtin_amdgcn_exp2f(dcl * na[6]);
            float e7 = __builtin_amdgcn_exp2f(dcl * na[7]);
            float fA = eA * rs;
            f[0] = fA; f[1] = fA; f[5] = fA;
            f[2] = e2 * rs; f[3] = e3 * rs; f[4] = e4 * rs;
            f[6] = e6 * rs; f[7] = e7 * rs;
        } else if constexpr (VAR == 1) {
            float fA = __builtin_amdgcn_exp2f(dcl * na[0]) * rs;
            f[0] = fA; f[1] = fA; f[5] = fA;
            f[2] = __builtin_amdgcn_exp2f(dcl * na[2]) * rs;
            f[3] = __builtin_amdgcn_exp2f(dcl * na[3]) * rs;
            f[4] = __builtin_amdgcn_exp2f(dcl * na[4]) * rs;
            f[6] = __builtin_amdgcn_exp2f(dcl * na[6]) * rs;
            f[7] = __builtin_amdgcn_exp2f(dcl * na[7]) * rs;
        } else {
#pragma unroll
            for (int m = 0; m < MM; ++m)
                f[m] = __builtin_amdgcn_exp2f(dcl * na[m]) * rs;
        }

        const float s[MM] = {s0.x, s0.y, s0.z, s0.w, s1.x, s1.y, s1.z, s1.w};
#pragma unroll
        for (int m = 0; m < MM; ++m)
            acc[m] = fmaf(f[m], s[m], acc[m]);
    }
}

// grid = (NN/BLOCK, C). Block: 256 i-rows x ntiles 64-wide j-tiles (compacted).
__global__ __launch_bounds__(BLOCK) void diff_partial(
    const float* __restrict__ pos, const float* __restrict__ radius,
    const float* __restrict__ secretion, const float* __restrict__ Dc,
    const float* __restrict__ Kd, const int* __restrict__ active,
    float* __restrict__ partial,   // C x NN x MM
    int ntiles)                    // tiles per chunk (1 when C=64)
{
    __shared__ float4 sj[JT];      // {x,y,z,r^2} of k-th ACTIVE j
    __shared__ float4 ss[JT * 2];  // premult secretion/(4*pi*D_m)
    __shared__ int s_nact;

    const int tid = threadIdx.x;
    const int i = blockIdx.x * BLOCK + tid;
    const int j0base = blockIdx.y * (JT * ntiles);

    float na[MM], invD[MM], acc[MM];
#pragma unroll
    for (int m = 0; m < MM; ++m) {
        float lam = sqrtf(Dc[m] / Kd[m]);
        na[m] = -LOG2E_F / lam;
        invD[m] = 1.0f / (FOUR_PI_F * Dc[m]);
        acc[m] = 0.0f;
    }
    const bool dup015 = (na[0] == na[1]) && (na[0] == na[5]);
    const bool chain =
        dup015 &&
        (fabsf(na[3] - 2.0f * na[2]) <= 4e-6f * fabsf(na[3])) &&
        (fabsf(na[4] - 2.0f * na[3]) <= 4e-6f * fabsf(na[4]));

    const float px = pos[i * 3 + 0];
    const float py = pos[i * 3 + 1];
    const float pz = pos[i * 3 + 2];

    for (int t = 0; t < ntiles; ++t) {
        const int j0 = j0base + t * JT;
        __syncthreads();  // protect LDS from previous tile's readers

        // Wave 0 (lanes 0..63) stages + compacts: lane tid owns j0+tid.
        if (tid < JT) {
            const int j = j0 + tid;
            const bool act = (active[j] != 0);
            const unsigned long long mask = __ballot(act);
            if (tid == 0) s_nact = __popcll(mask);
            if (act) {
                const int k = __popcll(mask & ((1ull << tid) - 1ull));
                const float r = radius[j];
                sj[k] = make_float4(pos[j * 3 + 0], pos[j * 3 + 1],
                                    pos[j * 3 + 2], r * r);
                const float4 s0 =
                    reinterpret_cast<const float4*>(secretion)[j * 2 + 0];
                const float4 s1 =
                    reinterpret_cast<const float4*>(secretion)[j * 2 + 1];
                ss[k * 2 + 0] = make_float4(s0.x * invD[0], s0.y * invD[1],
                                            s0.z * invD[2], s0.w * invD[3]);
                ss[k * 2 + 1] = make_float4(s1.x * invD[4], s1.y * invD[5],
                                            s1.z * invD[6], s1.w * invD[7]);
            }
        }
        __syncthreads();

        const int nact = s_nact;
        if (chain)       run_tile<2>(nact, sj, ss, px, py, pz, na, acc);
        else if (dup015) run_tile<1>(nact, sj, ss, px, py, pz, na, acc);
        else             run_tile<0>(nact, sj, ss, px, py, pz, na, acc);
    }

    float4* dst = reinterpret_cast<float4*>(
        partial + (size_t)blockIdx.y * NN * MM + (size_t)i * MM);
    dst[0] = make_float4(acc[0], acc[1], acc[2], acc[3]);
    dst[1] = make_float4(acc[4], acc[5], acc[6], acc[7]);
}

// Reduce: 512 blocks. tx = 16 outputs/block, ty = 16 parallel c-slices.
// Deep ILP per thread (C/16 = 4 independent loads) -> BW-bound, not latency.
__global__ __launch_bounds__(BLOCK) void diff_reduce(
    const float4* __restrict__ partial, float4* __restrict__ out, int C)
{
    __shared__ float4 red[16][16];
    const int tx = threadIdx.x & 15;
    const int ty = threadIdx.x >> 4;
    const int o = blockIdx.x * 16 + tx;  // 0 .. NN*MM/4-1

    float4 s = make_float4(0.f, 0.f, 0.f, 0.f);
    for (int c = ty; c < C; c += 16) {
        const float4 p = partial[(size_t)c * (NN * MM / 4) + o];
        s.x += p.x; s.y += p.y; s.z += p.z; s.w += p.w;
    }
    red[ty][tx] = s;
    __syncthreads();
#pragma unroll
    for (int h = 8; h >= 1; h >>= 1) {
        if (ty < h) {
            float4 a = red[ty + h][tx];
            red[ty][tx].x += a.x; red[ty][tx].y += a.y;
            red[ty][tx].z += a.z; red[ty][tx].w += a.w;
        }
        __syncthreads();
    }
    if (ty == 0) out[o] = red[0][tx];
}

extern "C" void kernel_launch(void* const* d_in, const int* in_sizes, int n_in,
                              void* d_out, int out_size, void* d_ws, size_t ws_size,
                              hipStream_t stream) {
    const float* pos       = (const float*)d_in[0];
    const float* radius    = (const float*)d_in[1];
    const float* secretion = (const float*)d_in[2];
    const float* Dc        = (const float*)d_in[3];
    const float* Kd        = (const float*)d_in[4];
    const int*   active    = (const int*)d_in[5];
    float* out = (float*)d_out;

    const size_t slice = (size_t)NN * MM * sizeof(float);  // 128 KB

    int C = CC;
    while (C > 4 && (size_t)C * slice > ws_size) C >>= 1;
    const int ntiles = NN / (C * JT);  // 1 at C=64

    float* partial = (float*)d_ws;
    dim3 grid(NN / BLOCK, C);
    diff_partial<<<grid, BLOCK, 0, stream>>>(pos, radius, secretion, Dc, Kd,
                                             active, partial, ntiles);
    diff_reduce<<<(NN * MM / 4) / 16, BLOCK, 0, stream>>>(
        (const float4*)partial, (float4*)out, C);
}

// Round 14
// 79.897 us; speedup vs baseline: 1.3300x; 1.0103x over previous
//
#include <hip/hip_runtime.h>
#include <math.h>

#define NN 4096
#define MM 8
#define BLOCK 256
#define CC 64                  // j-chunks (grid.y)
#define JT 64                  // j-tile size
#define FOUR_PI_F 12.566370614359172f
#define EPS_F 1e-8f
#define LOG2E_F 1.4426950408889634f

// out[i][m] = sum_j exp(-d_ij/lam_m)/(4*pi*D_m*d_ij) * secretion[j][m]*active[j]
// d_ij = max(sqrt(|p_i-p_j|^2+eps), r_j)
//
// R12 = R11 + (a) float2-paired m-section (SLP-friendly -> v_pk_*_f32),
// (b) skip the redundant leading barrier on the first tile.
// Structure: partial (16,64)=1024 blocks, 4 waves/SIMD, active-compacted
// 64-j LDS tiles; reduce 512 blocks, 16 outputs x 16 c-slices + LDS tree.
// Math: squared-domain clamp (one rsqrt); exp2(d*na); ballot-prefix
// compaction (order-preserving); runtime-gated specializations:
// VAR1 shares one exp2 across bit-equal lam (m 0,1,5); VAR2 adds the
// lam 20:10:5 chain (e3=e2^2, e4=e3^2): 4 exp2 + 1 rsq per pair.

template <int VAR>
__device__ __forceinline__ void run_tile(
    int nact, const float4* __restrict__ sj, const float4* __restrict__ ss,
    float px, float py, float pz, const float* __restrict__ na,
    float* __restrict__ acc)
{
#pragma unroll 2
    for (int jj = 0; jj < nact; ++jj) {
        const float4 pj = sj[jj];
        const float4 s0 = ss[jj * 2 + 0];
        const float4 s1 = ss[jj * 2 + 1];
        float dx = px - pj.x;
        float dy = py - pj.y;
        float dz = pz - pj.z;
        float d2 = fmaf(dx, dx, fmaf(dy, dy, fmaf(dz, dz, EPS_F)));
        float d2c = fmaxf(d2, pj.w);            // clamp in squared domain
        float rs = __builtin_amdgcn_rsqf(d2c);  // 1/dist
        float dcl = d2c * rs;                   // dist

        if constexpr (VAR == 2) {
            // exp args paired: (na0,na2)*dcl, (na6,na7)*dcl
            float a0 = dcl * na[0], a2 = dcl * na[2];
            float a6 = dcl * na[6], a7 = dcl * na[7];
            float eA = __builtin_amdgcn_exp2f(a0);
            float e2 = __builtin_amdgcn_exp2f(a2);
            float e6 = __builtin_amdgcn_exp2f(a6);
            float e7 = __builtin_amdgcn_exp2f(a7);
            float e3 = e2 * e2;   // lam3 = lam2/2
            float e4 = e3 * e3;   // lam4 = lam3/2
            // rs-muls paired: (eA,e2), (e3,e4), (e6,e7)
            float fA = eA * rs, f2 = e2 * rs;
            float f3 = e3 * rs, f4 = e4 * rs;
            float f6 = e6 * rs, f7 = e7 * rs;
            // accumulate as 4 float2 pairs: (0,1)(2,3)(4,5)(6,7)
            acc[0] = fmaf(fA, s0.x, acc[0]);
            acc[1] = fmaf(fA, s0.y, acc[1]);
            acc[2] = fmaf(f2, s0.z, acc[2]);
            acc[3] = fmaf(f3, s0.w, acc[3]);
            acc[4] = fmaf(f4, s1.x, acc[4]);
            acc[5] = fmaf(fA, s1.y, acc[5]);
            acc[6] = fmaf(f6, s1.z, acc[6]);
            acc[7] = fmaf(f7, s1.w, acc[7]);
        } else if constexpr (VAR == 1) {
            float fA = __builtin_amdgcn_exp2f(dcl * na[0]) * rs;
            float f2 = __builtin_amdgcn_exp2f(dcl * na[2]) * rs;
            float f3 = __builtin_amdgcn_exp2f(dcl * na[3]) * rs;
            float f4 = __builtin_amdgcn_exp2f(dcl * na[4]) * rs;
            float f6 = __builtin_amdgcn_exp2f(dcl * na[6]) * rs;
            float f7 = __builtin_amdgcn_exp2f(dcl * na[7]) * rs;
            acc[0] = fmaf(fA, s0.x, acc[0]);
            acc[1] = fmaf(fA, s0.y, acc[1]);
            acc[2] = fmaf(f2, s0.z, acc[2]);
            acc[3] = fmaf(f3, s0.w, acc[3]);
            acc[4] = fmaf(f4, s1.x, acc[4]);
            acc[5] = fmaf(fA, s1.y, acc[5]);
            acc[6] = fmaf(f6, s1.z, acc[6]);
            acc[7] = fmaf(f7, s1.w, acc[7]);
        } else {
            const float s[MM] = {s0.x, s0.y, s0.z, s0.w,
                                 s1.x, s1.y, s1.z, s1.w};
#pragma unroll
            for (int m = 0; m < MM; ++m)
                acc[m] = fmaf(__builtin_amdgcn_exp2f(dcl * na[m]) * rs,
                              s[m], acc[m]);
        }
    }
}

// grid = (NN/BLOCK, C). Block: 256 i-rows x ntiles 64-wide j-tiles (compacted).
__global__ __launch_bounds__(BLOCK) void diff_partial(
    const float* __restrict__ pos, const float* __restrict__ radius,
    const float* __restrict__ secretion, const float* __restrict__ Dc,
    const float* __restrict__ Kd, const int* __restrict__ active,
    float* __restrict__ partial,   // C x NN x MM
    int ntiles)                    // tiles per chunk (1 when C=64)
{
    __shared__ float4 sj[JT];      // {x,y,z,r^2} of k-th ACTIVE j
    __shared__ float4 ss[JT * 2];  // premult secretion/(4*pi*D_m)
    __shared__ int s_nact;

    const int tid = threadIdx.x;
    const int i = blockIdx.x * BLOCK + tid;
    const int j0base = blockIdx.y * (JT * ntiles);

    float na[MM], invD[MM], acc[MM];
#pragma unroll
    for (int m = 0; m < MM; ++m) {
        float lam = sqrtf(Dc[m] / Kd[m]);   // exact div+sqrt: keeps the
        na[m] = -LOG2E_F / lam;             // dup015/chain bit-equality gates
        invD[m] = 1.0f / (FOUR_PI_F * Dc[m]);
        acc[m] = 0.0f;
    }
    const bool dup015 = (na[0] == na[1]) && (na[0] == na[5]);
    const bool chain =
        dup015 &&
        (fabsf(na[3] - 2.0f * na[2]) <= 4e-6f * fabsf(na[3])) &&
        (fabsf(na[4] - 2.0f * na[3]) <= 4e-6f * fabsf(na[4]));

    const float px = pos[i * 3 + 0];
    const float py = pos[i * 3 + 1];
    const float pz = pos[i * 3 + 2];

    for (int t = 0; t < ntiles; ++t) {
        const int j0 = j0base + t * JT;
        if (t) __syncthreads();  // protect LDS from previous tile's readers

        // Wave 0 (lanes 0..63) stages + compacts: lane tid owns j0+tid.
        if (tid < JT) {
            const int j = j0 + tid;
            const bool act = (active[j] != 0);
            const unsigned long long mask = __ballot(act);
            if (tid == 0) s_nact = __popcll(mask);
            if (act) {
                const int k = __popcll(mask & ((1ull << tid) - 1ull));
                const float r = radius[j];
                sj[k] = make_float4(pos[j * 3 + 0], pos[j * 3 + 1],
                                    pos[j * 3 + 2], r * r);
                const float4 s0 =
                    reinterpret_cast<const float4*>(secretion)[j * 2 + 0];
                const float4 s1 =
                    reinterpret_cast<const float4*>(secretion)[j * 2 + 1];
                ss[k * 2 + 0] = make_float4(s0.x * invD[0], s0.y * invD[1],
                                            s0.z * invD[2], s0.w * invD[3]);
                ss[k * 2 + 1] = make_float4(s1.x * invD[4], s1.y * invD[5],
                                            s1.z * invD[6], s1.w * invD[7]);
            }
        }
        __syncthreads();

        const int nact = s_nact;
        if (chain)       run_tile<2>(nact, sj, ss, px, py, pz, na, acc);
        else if (dup015) run_tile<1>(nact, sj, ss, px, py, pz, na, acc);
        else             run_tile<0>(nact, sj, ss, px, py, pz, na, acc);
    }

    float4* dst = reinterpret_cast<float4*>(
        partial + (size_t)blockIdx.y * NN * MM + (size_t)i * MM);
    dst[0] = make_float4(acc[0], acc[1], acc[2], acc[3]);
    dst[1] = make_float4(acc[4], acc[5], acc[6], acc[7]);
}

// Reduce: 512 blocks. tx = 16 outputs/block, ty = 16 parallel c-slices.
__global__ __launch_bounds__(BLOCK) void diff_reduce(
    const float4* __restrict__ partial, float4* __restrict__ out, int C)
{
    __shared__ float4 red[16][16];
    const int tx = threadIdx.x & 15;
    const int ty = threadIdx.x >> 4;
    const int o = blockIdx.x * 16 + tx;  // 0 .. NN*MM/4-1

    float4 s = make_float4(0.f, 0.f, 0.f, 0.f);
    for (int c = ty; c < C; c += 16) {
        const float4 p = partial[(size_t)c * (NN * MM / 4) + o];
        s.x += p.x; s.y += p.y; s.z += p.z; s.w += p.w;
    }
    red[ty][tx] = s;
    __syncthreads();
#pragma unroll
    for (int h = 8; h >= 1; h >>= 1) {
        if (ty < h) {
            float4 a = red[ty + h][tx];
            red[ty][tx].x += a.x; red[ty][tx].y += a.y;
            red[ty][tx].z += a.z; red[ty][tx].w += a.w;
        }
        __syncthreads();
    }
    if (ty == 0) out[o] = red[0][tx];
}

extern "C" void kernel_launch(void* const* d_in, const int* in_sizes, int n_in,
                              void* d_out, int out_size, void* d_ws, size_t ws_size,
                              hipStream_t stream) {
    const float* pos       = (const float*)d_in[0];
    const float* radius    = (const float*)d_in[1];
    const float* secretion = (const float*)d_in[2];
    const float* Dc        = (const float*)d_in[3];
    const float* Kd        = (const float*)d_in[4];
    const int*   active    = (const int*)d_in[5];
    float* out = (float*)d_out;

    const size_t slice = (size_t)NN * MM * sizeof(float);  // 128 KB

    int C = CC;
    while (C > 4 && (size_t)C * slice > ws_size) C >>= 1;
    const int ntiles = NN / (C * JT);  // 1 at C=64

    float* partial = (float*)d_ws;
    dim3 grid(NN / BLOCK, C);
    diff_partial<<<grid, BLOCK, 0, stream>>>(pos, radius, secretion, Dc, Kd,
                                             active, partial, ntiles);
    diff_reduce<<<(NN * MM / 4) / 16, BLOCK, 0, stream>>>(
        (const float4*)partial, (float4*)out, C);
}